// Round 5
// baseline (461.581 us; speedup 1.0000x reference)
//
#include <hip/hip_runtime.h>

// S5 forward: GEMM1 (u @ Bbar^T) -> chunked complex scan -> GEMM2 (xs @ C'^T) + D*u
// B=8, L=4096, H=1024, P=512.  M = B*L = 32768, K = 1024, N = 1024 for both GEMMs.
// GEMM: 256x256 tile, 8-phase counted-vmcnt schedule; snake-order quadrant phases with
// A/B fragment register reuse (28 ds_read_b128/lane/tile instead of 48).

#define Bsz 8
#define Lseq 4096
#define Hdim 1024
#define Pdim 512
#define NCHUNK 64
#define CHUNK 64
#define MROWS 32768

typedef __attribute__((ext_vector_type(8))) __bf16 bf16x8;
typedef __attribute__((ext_vector_type(4))) float f32x4;

__device__ __forceinline__ unsigned short f2bf(float f) {
  union { float f; unsigned u; } v; v.f = f;
  unsigned r = v.u + 0x7fffu + ((v.u >> 16) & 1u);
  return (unsigned short)(r >> 16);
}
__device__ __forceinline__ float bf2f(unsigned short s) {
  union { unsigned u; float f; } v; v.u = ((unsigned)s) << 16;
  return v.f;
}

__device__ __forceinline__ void gld_lds16(const void* g, void* l) {
  __builtin_amdgcn_global_load_lds(
      (const __attribute__((address_space(1))) unsigned int*)g,
      (__attribute__((address_space(3))) unsigned int*)l, 16, 0, 0);
}

// ---------------- setup: a = exp(Lambda*step), aS = a^CHUNK, g = (a-1)/Lambda ----------
__global__ void k_setup(const float* __restrict__ Lre_in, const float* __restrict__ Lim_in,
                        const float* __restrict__ log_step,
                        float2* __restrict__ a_arr, float2* __restrict__ aS_arr,
                        float2* __restrict__ g_arr) {
  int p = threadIdx.x;
  if (p >= Pdim) return;
  float lre = fminf(Lre_in[p], -1e-4f);
  float lim = Lim_in[p];
  float step = expf(log_step[p]);
  float zr = lre * step, zi = lim * step;
  float er = expf(zr);
  float ar = er * cosf(zi), ai = er * sinf(zi);
  a_arr[p] = make_float2(ar, ai);
  float erS = expf(zr * (float)CHUNK);
  aS_arr[p] = make_float2(erS * cosf(zi * (float)CHUNK), erS * sinf(zi * (float)CHUNK));
  float den = lre * lre + lim * lim;
  float nr = ar - 1.0f, ni = ai;
  g_arr[p] = make_float2((nr * lre + ni * lim) / den, (ni * lre - nr * lim) / den);
}

// ---------------- prep Bbar' (N=2P rows, K=H) bf16 ----------------
__global__ void k_prep_B(const float* __restrict__ Bin, const float2* __restrict__ g_arr,
                         unsigned short* __restrict__ Bbar2) {
  int idx = blockIdx.x * 256 + threadIdx.x;   // over P*H = 524288
  int p = idx >> 10;
  int h = idx & 1023;
  float B0 = Bin[2 * idx];      // B[p,h,0] : p*H*2 + h*2
  float B1 = Bin[2 * idx + 1];
  float2 g = g_arr[p];
  Bbar2[(size_t)p * Hdim + h]            = f2bf(g.x * B0 - g.y * B1);
  Bbar2[(size_t)(Pdim + p) * Hdim + h]   = f2bf(g.x * B1 + g.y * B0);
}

// ---------------- prep C' (N=H rows, K=2P) bf16 : [C_re | -C_im] ----------------
__global__ void k_prep_C(const float* __restrict__ Cin, unsigned short* __restrict__ C2m) {
  int idx = blockIdx.x * 256 + threadIdx.x;   // over H*P = 524288
  int h = idx >> 9;
  int p = idx & 511;
  float C0 = Cin[2 * idx];      // C[h,p,0] : h*P*2 + p*2
  float C1 = Cin[2 * idx + 1];
  C2m[(size_t)h * 1024 + p]        = f2bf(C0);
  C2m[(size_t)h * 1024 + 512 + p]  = f2bf(-C1);
}

// ---------------- u fp32 -> bf16 (grid-stride, 16 float4/thread) ----------------
__global__ void k_cvt_u(const float* __restrict__ u, unsigned short* __restrict__ ub) {
  size_t tidg = (size_t)blockIdx.x * 256 + threadIdx.x;
#pragma unroll 4
  for (int it = 0; it < 16; ++it) {
    size_t i = (tidg + (size_t)it * 524288) * 4;
    float4 v = *(const float4*)(u + i);
    ushort4 o;
    o.x = f2bf(v.x); o.y = f2bf(v.y); o.z = f2bf(v.z); o.w = f2bf(v.w);
    *(ushort4*)(ub + i) = o;
  }
}

// ---------------- 256x256 bf16 GEMM, B^T input, 8-phase counted-vmcnt schedule -------
// C[m,n] = sum_k A[m,k]*Bt[n,k];  M=32768, N=1024, K=1024.
// 512 threads = 8 waves: wr = w>>2 (m-half, 128 rows), wc = w&3 (n-quarter, 64 cols).
// Per wave: 8 m-frags x 4 n-frags of 16x16, K-tile BK=64 (2 k-slots of 32).
// LDS: 2 buffers x {A 32KB | B 32KB} = 128 KB. XOR-swizzle byte ^= ((row&7)<<4) applied
// on the GLOBAL source (linear gld_lds dest, rule #21) and on ds_read addresses.
// Snake phase order (0,0)->(0,1)->(1,1)->(1,0): A-frags reused across phases 0-1 and
// 2-3, B-frags reused across 1-2; ds volume 28 b128/lane/tile (was 48) -- the phase
// pacing item is LDS read BW, MFMA/LDS-service ratio sets the MfmaUtil ceiling.
// Staging of tile t+1: A in phase 0, B in phase 1; single vmcnt(0) at end of phase 3
// (loads are then >=2 phases old); loads stay in flight across 6 barriers.
// EPI 0: bf16 store via full-tile LDS transpose.  EPI 1: fp32 = acc + D[n]*u[m,n].

#define STAGE_A(t_, bo_)                                                    \
  do {                                                                      \
    _Pragma("unroll")                                                       \
    for (int jj = 0; jj < 4; jj++)                                          \
      gld_lds16(pa[jj] + (t_) * 64, smc + (bo_) + (jj * 512 + tid) * 16);   \
  } while (0)

#define STAGE_B(t_, bo_)                                                    \
  do {                                                                      \
    _Pragma("unroll")                                                       \
    for (int jj = 0; jj < 4; jj++)                                          \
      gld_lds16(pb[jj] + (t_) * 64, smc + (bo_) + 32768 + (jj * 512 + tid) * 16); \
  } while (0)

#define PHASE_Q(mh, nh, LA, LB, PRE, POST)                                  \
  {                                                                         \
    const char* bb_ = smc + bufo;                                           \
    if (LA) {                                                               \
      _Pragma("unroll")                                                     \
      for (int i_ = 0; i_ < 4; i_++) {                                      \
        int rb_ = aRowByte + ((mh) * 4 + i_) * 2048;                        \
        af[i_][0] = *(const bf16x8*)(bb_ + rb_ + k0);                       \
        af[i_][1] = *(const bf16x8*)(bb_ + rb_ + k1);                       \
      }                                                                     \
    }                                                                       \
    if (LB) {                                                               \
      _Pragma("unroll")                                                     \
      for (int j_ = 0; j_ < 2; j_++) {                                      \
        int rb_ = bRowByte + ((nh) * 2 + j_) * 2048;                        \
        bfv[j_][0] = *(const bf16x8*)(bb_ + rb_ + k0);                      \
        bfv[j_][1] = *(const bf16x8*)(bb_ + rb_ + k1);                      \
      }                                                                     \
    }                                                                       \
    PRE;                                                                    \
    __builtin_amdgcn_s_barrier();                                           \
    asm volatile("s_waitcnt lgkmcnt(0)" ::: "memory");                      \
    __builtin_amdgcn_sched_barrier(0);                                      \
    __builtin_amdgcn_s_setprio(1);                                          \
    _Pragma("unroll")                                                       \
    for (int i_ = 0; i_ < 4; i_++)                                          \
      _Pragma("unroll")                                                     \
      for (int j_ = 0; j_ < 2; j_++) {                                      \
        acc[(mh) * 4 + i_][(nh) * 2 + j_] =                                 \
            __builtin_amdgcn_mfma_f32_16x16x32_bf16(                        \
                af[i_][0], bfv[j_][0], acc[(mh) * 4 + i_][(nh) * 2 + j_], 0, 0, 0); \
        acc[(mh) * 4 + i_][(nh) * 2 + j_] =                                 \
            __builtin_amdgcn_mfma_f32_16x16x32_bf16(                        \
                af[i_][1], bfv[j_][1], acc[(mh) * 4 + i_][(nh) * 2 + j_], 0, 0, 0); \
      }                                                                     \
    __builtin_amdgcn_s_setprio(0);                                          \
    POST;                                                                   \
    __builtin_amdgcn_s_barrier();                                           \
  }

template <int EPI>
__global__ __launch_bounds__(512, 2) void gemm256(const unsigned short* __restrict__ A,
                                                  const unsigned short* __restrict__ Bt,
                                                  void* __restrict__ Cout,
                                                  const float* __restrict__ uin,
                                                  const float* __restrict__ Dvec) {
  const int K = 1024;
  __shared__ __align__(16) unsigned short sm[65536];   // 128 KB
  char* smc = (char*)sm;

  int tid = threadIdx.x;
  int lane = tid & 63;
  int w = tid >> 6;            // 0..7
  int wr = w >> 2, wc = w & 3; // m-half / n-quarter
  int quad = lane >> 4;        // 0..3 (k-chunk)
  int mrow = lane & 15;        // row-within-frag (A) / col (C)

  int wg = blockIdx.x;
  size_t rowBase = (size_t)(wg >> 2) * 256;   // m-tile
  size_t colBase = (size_t)(wg & 3) * 256;    // n-tile

  f32x4 acc[8][4];
#pragma unroll
  for (int i = 0; i < 8; i++)
#pragma unroll
    for (int j = 0; j < 4; j++) acc[i][j] = (f32x4){0.f, 0.f, 0.f, 0.f};

  // fragment registers, live across phases (snake reuse)
  bf16x8 af[4][2], bfv[2][2];

  // staging: thread tid, load jj covers LDS chunk ci = jj*512+tid of the 32KB tile.
  // LDS (row, chunk) = (ci>>3, ci&7); source chunk pre-swizzled: cs = (tid&7)^((tid>>3)&7)
  int cs = (tid & 7) ^ ((tid >> 3) & 7);
  int rT = tid >> 3;            // 0..63 (row within 64-row group jj)
  const unsigned short* pa[4];
  const unsigned short* pb[4];
#pragma unroll
  for (int jj = 0; jj < 4; jj++) {
    pa[jj] = A  + (rowBase + jj * 64 + rT) * K + cs * 8;
    pb[jj] = Bt + (colBase + jj * 64 + rT) * K + cs * 8;
  }

  // frag-read constants: byte col = (ks*64 + quad*16) ^ ((row&7)<<4); row&7 == mrow&7
  int axor = (mrow & 7) << 4;
  int k0 = (quad * 16) ^ axor;
  int k1 = (64 + quad * 16) ^ axor;
  int aRowByte = (wr * 128 + mrow) * 128;            // + fm*2048
  int bRowByte = 32768 + (wc * 64 + mrow) * 128;     // + fn*2048

  // prologue: stage tile 0 into buffer 0, drain, sync
  STAGE_A(0, 0);
  STAGE_B(0, 0);
  asm volatile("s_waitcnt vmcnt(0)" ::: "memory");
  __builtin_amdgcn_s_barrier();

  for (int t = 0; t < 16; ++t) {
    int bufo = (t & 1) * 65536;
    int nbo = bufo ^ 65536;
    PHASE_Q(0, 0, 1, 1, if (t < 15) STAGE_A(t + 1, nbo), );
    PHASE_Q(0, 1, 0, 1, if (t < 15) STAGE_B(t + 1, nbo), );
    PHASE_Q(1, 1, 1, 0, , );
    PHASE_Q(1, 0, 0, 1, , asm volatile("s_waitcnt vmcnt(0)" ::: "memory"));
  }

  // epilogue.  C/D frag layout: m = quad*4 + r, n = mrow (within 16x16)
  if (EPI == 0) {
    // bf16 out via full 256x256 LDS transpose -> 512B-row coalesced stores
    unsigned short* O = (unsigned short*)Cout;
    __syncthreads();
#pragma unroll
    for (int fm = 0; fm < 8; fm++)
#pragma unroll
      for (int fn = 0; fn < 4; fn++)
#pragma unroll
        for (int r = 0; r < 4; r++) {
          int m_l = wr * 128 + fm * 16 + quad * 4 + r;
          int n_l = wc * 64 + fn * 16 + mrow;
          sm[m_l * 256 + n_l] = f2bf(acc[fm][fn][r]);
        }
    __syncthreads();
#pragma unroll
    for (int it = 0; it < 16; it++) {
      int cid = it * 512 + tid;          // 8192 chunks: 256 rows x 32 x 16B
      int r = cid >> 5;
      int c = cid & 31;
      uint4 v = *(const uint4*)(sm + r * 256 + c * 8);
      *(uint4*)(O + (rowBase + r) * 1024 + colBase + c * 8) = v;
    }
  } else {
    float* O = (float*)Cout;
    size_t mBase = rowBase + wr * 128 + quad * 4;
    size_t nBase = colBase + wc * 64 + mrow;
#pragma unroll
    for (int fm = 0; fm < 8; fm++)
#pragma unroll
      for (int fn = 0; fn < 4; fn++) {
        size_t n = nBase + fn * 16;
        float dv = Dvec[n];
#pragma unroll
        for (int r = 0; r < 4; r++) {
          size_t m = mBase + fm * 16 + r;
          O[m * 1024 + n] = acc[fm][fn][r] + dv * uin[m * 1024 + n];
        }
      }
  }
}

// ---------------- scan phase 1: per-chunk aggregate T_c ----------------
// 1 chunk per 256-thread block (512 blocks), 2 p-states/thread (4B loads).
__global__ void k_scan1(const unsigned short* __restrict__ Bu, const float2* __restrict__ a_arr,
                        float* __restrict__ carryT) {
  int bc = blockIdx.x;                       // b*NCHUNK + c, 0..511
  int p0 = threadIdx.x * 2;                  // 0,2,..,510
  int b = bc >> 6, c = bc & 63;
  float2 a0 = a_arr[p0], a1 = a_arr[p0 + 1];
  const unsigned short* bu = Bu + ((size_t)b * Lseq + (size_t)c * CHUNK) * 1024;
  float tr0 = 0.f, ti0 = 0.f, tr1 = 0.f, ti1 = 0.f;
#pragma unroll 8
  for (int l = 0; l < CHUNK; l++) {
    unsigned vr = *(const unsigned*)(bu + (size_t)l * 1024 + p0);
    unsigned vi = *(const unsigned*)(bu + (size_t)l * 1024 + 512 + p0);
    float br0 = bf2f((unsigned short)vr), br1 = bf2f((unsigned short)(vr >> 16));
    float bi0 = bf2f((unsigned short)vi), bi1 = bf2f((unsigned short)(vi >> 16));
    float nr0 = fmaf(a0.x, tr0, fmaf(-a0.y, ti0, br0));
    ti0 = fmaf(a0.x, ti0, fmaf(a0.y, tr0, bi0));
    tr0 = nr0;
    float nr1 = fmaf(a1.x, tr1, fmaf(-a1.y, ti1, br1));
    ti1 = fmaf(a1.x, ti1, fmaf(a1.y, tr1, bi1));
    tr1 = nr1;
  }
  *(float2*)(carryT + (size_t)bc * 1024 + p0) = make_float2(tr0, tr1);
  *(float2*)(carryT + (size_t)bc * 1024 + 512 + p0) = make_float2(ti0, ti1);
}

// ---------------- scan phase 2: wave-parallel Kogge-Stone over chunk carries ----------
// One wave per (b,p): lane = chunk c. Inclusive KS with uniform multiplier s^d
// (repeated squaring), then shift to exclusive. 4096 waves = 1024 blocks.
__global__ void k_scan2(const float* __restrict__ carryT, const float2* __restrict__ aS_arr,
                        float* __restrict__ prefix) {
  int wid = blockIdx.x * 4 + (threadIdx.x >> 6);   // 0..4095
  int lane = threadIdx.x & 63;                     // chunk index c
  int b = wid >> 9;                                // 0..7
  int p = wid & 511;                               // 0..511
  float2 s = aS_arr[p];
  size_t o = ((size_t)(b * NCHUNK + lane)) * 1024 + p;
  float tr = carryT[o], ti = carryT[o + 512];
  // inclusive scan: S_c = sum_{j<=c} s^(c-j) T_j
  float mr = s.x, mi = s.y;                        // s^d, starting d=1
#pragma unroll
  for (int d = 1; d < 64; d <<= 1) {
    float ur = __shfl_up(tr, d, 64);
    float ui = __shfl_up(ti, d, 64);
    if (lane >= d) {
      tr = fmaf(mr, ur, fmaf(-mi, ui, tr));
      ti = fmaf(mr, ui, fmaf(mi, ur, ti));
    }
    float nmr = mr * mr - mi * mi;                 // s^d -> s^(2d)
    mi = 2.f * mr * mi;
    mr = nmr;
  }
  // exclusive: prefix before chunk c = S_{c-1}; chunk 0 starts at 0
  float er = __shfl_up(tr, 1, 64);
  float ei = __shfl_up(ti, 1, 64);
  if (lane == 0) { er = 0.f; ei = 0.f; }
  prefix[o] = er;
  prefix[o + 512] = ei;
}

// ---------------- scan phase 3: replay chunk from carry-in, write xs bf16 ----------
// 1 chunk per 256-thread block (512 blocks), 2 p-states/thread.
__global__ void k_scan3(const unsigned short* __restrict__ Bu, const float2* __restrict__ a_arr,
                        const float* __restrict__ prefix, unsigned short* __restrict__ xs) {
  int bc = blockIdx.x;
  int p0 = threadIdx.x * 2;
  int b = bc >> 6, c = bc & 63;
  float2 a0 = a_arr[p0], a1 = a_arr[p0 + 1];
  size_t base = ((size_t)b * Lseq + (size_t)c * CHUNK) * 1024;
  size_t po = (size_t)bc * 1024 + p0;
  float2 xrv = *(const float2*)(prefix + po);
  float2 xiv = *(const float2*)(prefix + po + 512);
  float xr0 = xrv.x, xr1 = xrv.y, xi0 = xiv.x, xi1 = xiv.y;
#pragma unroll 8
  for (int l = 0; l < CHUNK; l++) {
    unsigned vr = *(const unsigned*)(Bu + base + (size_t)l * 1024 + p0);
    unsigned vi = *(const unsigned*)(Bu + base + (size_t)l * 1024 + 512 + p0);
    float br0 = bf2f((unsigned short)vr), br1 = bf2f((unsigned short)(vr >> 16));
    float bi0 = bf2f((unsigned short)vi), bi1 = bf2f((unsigned short)(vi >> 16));
    float nr0 = fmaf(a0.x, xr0, fmaf(-a0.y, xi0, br0));
    xi0 = fmaf(a0.x, xi0, fmaf(a0.y, xr0, bi0));
    xr0 = nr0;
    float nr1 = fmaf(a1.x, xr1, fmaf(-a1.y, xi1, br1));
    xi1 = fmaf(a1.x, xi1, fmaf(a1.y, xr1, bi1));
    xr1 = nr1;
    unsigned orv = (unsigned)f2bf(xr0) | ((unsigned)f2bf(xr1) << 16);
    unsigned oiv = (unsigned)f2bf(xi0) | ((unsigned)f2bf(xi1) << 16);
    *(unsigned*)(xs + base + (size_t)l * 1024 + p0) = orv;
    *(unsigned*)(xs + base + (size_t)l * 1024 + 512 + p0) = oiv;
  }
}

extern "C" void kernel_launch(void* const* d_in, const int* in_sizes, int n_in,
                              void* d_out, int out_size, void* d_ws, size_t ws_size,
                              hipStream_t stream) {
  const float* u     = (const float*)d_in[0];
  const float* Lre   = (const float*)d_in[1];
  const float* Lim   = (const float*)d_in[2];
  const float* Bin   = (const float*)d_in[3];
  const float* Cin   = (const float*)d_in[4];
  const float* Dvec  = (const float*)d_in[5];
  const float* lstep = (const float*)d_in[6];

  char* ws = (char*)d_ws;
  // ws layout (~75.5 MB):
  unsigned short* ubf_xs = (unsigned short*)(ws);                    // 67,108,864 B (u_bf16, later reused as xs)
  unsigned short* Bbar2  = (unsigned short*)(ws + 67108864);         // 2 MB
  unsigned short* C2m    = (unsigned short*)(ws + 69206016);         // 2 MB
  float*          carryT = (float*)(ws + 71303168);                  // 2 MB
  float*          prefix = (float*)(ws + 73400320);                  // 2 MB
  float2*         a_arr  = (float2*)(ws + 75497472);
  float2*         aS_arr = (float2*)(ws + 75501568);
  float2*         g_arr  = (float2*)(ws + 75505664);

  // Bu lives in d_out (bf16, 67MB of the 134MB out buffer); dead before GEMM2 writes out.
  unsigned short* Bu = (unsigned short*)d_out;

  k_setup<<<1, 512, 0, stream>>>(Lre, Lim, lstep, a_arr, aS_arr, g_arr);
  k_prep_B<<<2048, 256, 0, stream>>>(Bin, g_arr, Bbar2);
  k_prep_C<<<2048, 256, 0, stream>>>(Cin, C2m);
  k_cvt_u<<<2048, 256, 0, stream>>>(u, ubf_xs);

  gemm256<0><<<512, 512, 0, stream>>>(ubf_xs, Bbar2, (void*)Bu, nullptr, nullptr);

  k_scan1<<<512, 256, 0, stream>>>(Bu, a_arr, carryT);
  k_scan2<<<1024, 256, 0, stream>>>(carryT, aS_arr, prefix);
  k_scan3<<<512, 256, 0, stream>>>(Bu, a_arr, prefix, ubf_xs);

  gemm256<1><<<512, 512, 0, stream>>>(ubf_xs, C2m, d_out, u, Dvec);
}

// Round 6
// 434.731 us; speedup vs baseline: 1.0618x; 1.0618x over previous
//
#include <hip/hip_runtime.h>

// S5 forward: GEMM1 (u @ Bbar^T, fused chunk-aggregate scan) -> scan2 -> scan3 -> GEMM2.
// B=8, L=4096, H=1024, P=512.  M = B*L = 32768, K = 1024, N = 1024 for both GEMMs.
// Complex state layout is INTERLEAVED: column 2q = re(q), 2q+1 = im(q).  This makes each
// GEMM1 256-col n-tile hold 128 complete complex states, so the per-chunk scan aggregate
// (old k_scan1: a full 64MB HBM re-read) is computed from the epilogue's LDS tile free.

#define Bsz 8
#define Lseq 4096
#define Hdim 1024
#define Pdim 512
#define NCHUNK 64
#define CHUNK 64
#define MROWS 32768

typedef __attribute__((ext_vector_type(8))) __bf16 bf16x8;
typedef __attribute__((ext_vector_type(4))) float f32x4;

__device__ __forceinline__ unsigned short f2bf(float f) {
  union { float f; unsigned u; } v; v.f = f;
  unsigned r = v.u + 0x7fffu + ((v.u >> 16) & 1u);
  return (unsigned short)(r >> 16);
}
__device__ __forceinline__ float bf2f(unsigned short s) {
  union { unsigned u; float f; } v; v.u = ((unsigned)s) << 16;
  return v.f;
}

__device__ __forceinline__ void gld_lds16(const void* g, void* l) {
  __builtin_amdgcn_global_load_lds(
      (const __attribute__((address_space(1))) unsigned int*)g,
      (__attribute__((address_space(3))) unsigned int*)l, 16, 0, 0);
}

// ---------------- setup: a = exp(Lambda*step), aS = a^CHUNK, g = (a-1)/Lambda ----------
__global__ void k_setup(const float* __restrict__ Lre_in, const float* __restrict__ Lim_in,
                        const float* __restrict__ log_step,
                        float2* __restrict__ a_arr, float2* __restrict__ aS_arr,
                        float2* __restrict__ g_arr) {
  int p = threadIdx.x;
  if (p >= Pdim) return;
  float lre = fminf(Lre_in[p], -1e-4f);
  float lim = Lim_in[p];
  float step = expf(log_step[p]);
  float zr = lre * step, zi = lim * step;
  float er = expf(zr);
  float ar = er * cosf(zi), ai = er * sinf(zi);
  a_arr[p] = make_float2(ar, ai);
  float erS = expf(zr * (float)CHUNK);
  aS_arr[p] = make_float2(erS * cosf(zi * (float)CHUNK), erS * sinf(zi * (float)CHUNK));
  float den = lre * lre + lim * lim;
  float nr = ar - 1.0f, ni = ai;
  g_arr[p] = make_float2((nr * lre + ni * lim) / den, (ni * lre - nr * lim) / den);
}

// ---------------- prep Bbar' (N=2P rows interleaved, K=H) bf16 ----------------
__global__ void k_prep_B(const float* __restrict__ Bin, const float2* __restrict__ g_arr,
                         unsigned short* __restrict__ Bbar2) {
  int idx = blockIdx.x * 256 + threadIdx.x;   // over P*H = 524288
  int p = idx >> 10;
  int h = idx & 1023;
  float B0 = Bin[2 * idx];      // B[p,h,0] : p*H*2 + h*2
  float B1 = Bin[2 * idx + 1];
  float2 g = g_arr[p];
  Bbar2[(size_t)(2 * p) * Hdim + h]     = f2bf(g.x * B0 - g.y * B1);   // re row
  Bbar2[(size_t)(2 * p + 1) * Hdim + h] = f2bf(g.x * B1 + g.y * B0);   // im row
}

// ---------------- prep C' (N=H rows, K=2P interleaved) bf16 : [Cr, -Ci] pairs ---------
__global__ void k_prep_C(const float* __restrict__ Cin, unsigned short* __restrict__ C2m) {
  int idx = blockIdx.x * 256 + threadIdx.x;   // over H*P = 524288
  int h = idx >> 9;
  int p = idx & 511;
  float C0 = Cin[2 * idx];      // C[h,p,0] : h*P*2 + p*2
  float C1 = Cin[2 * idx + 1];
  C2m[(size_t)h * 1024 + 2 * p]     = f2bf(C0);
  C2m[(size_t)h * 1024 + 2 * p + 1] = f2bf(-C1);
}

// ---------------- u fp32 -> bf16 ----------------
__global__ void k_cvt_u(const float* __restrict__ u, unsigned short* __restrict__ ub) {
  size_t i = ((size_t)blockIdx.x * 256 + threadIdx.x) * 4;
  float4 v = *(const float4*)(u + i);
  ushort4 o;
  o.x = f2bf(v.x); o.y = f2bf(v.y); o.z = f2bf(v.z); o.w = f2bf(v.w);
  *(ushort4*)(ub + i) = o;
}

// ---------------- 256x256 bf16 GEMM, B^T input, 8-phase counted-vmcnt schedule -------
// C[m,n] = sum_k A[m,k]*Bt[n,k];  M=32768, N=1024, K=1024.
// 512 threads = 8 waves: wr = w>>2 (m-half, 128 rows), wc = w&3 (n-quarter, 64 cols).
// LDS: 2 buffers x {A 32KB | B 32KB} = 128 KB. XOR-swizzle byte ^= ((row&7)<<4) via
// pre-swizzled global source (linear gld_lds dest) + swizzled ds_read addresses.
// Snake phase order (0,0)->(0,1)->(1,1)->(1,0) with A/B fragment register reuse.
// Staging of tile t+1: A in phase 0, B in phase 1; single vmcnt(0) at end of phase 3.
// EPI 0: bf16 store via full-tile LDS transpose + FUSED per-chunk scan aggregate
//        (T_c for the 4 chunks x 128 complex states of this tile -> carry2).
// EPI 1: fp32 = acc + D[n]*u[m,n].

#define STAGE_A(t_, bo_)                                                    \
  do {                                                                      \
    _Pragma("unroll")                                                       \
    for (int jj = 0; jj < 4; jj++)                                          \
      gld_lds16(pa[jj] + (t_) * 64, smc + (bo_) + (jj * 512 + tid) * 16);   \
  } while (0)

#define STAGE_B(t_, bo_)                                                    \
  do {                                                                      \
    _Pragma("unroll")                                                       \
    for (int jj = 0; jj < 4; jj++)                                          \
      gld_lds16(pb[jj] + (t_) * 64, smc + (bo_) + 32768 + (jj * 512 + tid) * 16); \
  } while (0)

#define PHASE_Q(mh, nh, LA, LB, PRE, POST)                                  \
  {                                                                         \
    const char* bb_ = smc + bufo;                                           \
    if (LA) {                                                               \
      _Pragma("unroll")                                                     \
      for (int i_ = 0; i_ < 4; i_++) {                                      \
        int rb_ = aRowByte + ((mh) * 4 + i_) * 2048;                        \
        af[i_][0] = *(const bf16x8*)(bb_ + rb_ + k0);                       \
        af[i_][1] = *(const bf16x8*)(bb_ + rb_ + k1);                       \
      }                                                                     \
    }                                                                       \
    if (LB) {                                                               \
      _Pragma("unroll")                                                     \
      for (int j_ = 0; j_ < 2; j_++) {                                      \
        int rb_ = bRowByte + ((nh) * 2 + j_) * 2048;                        \
        bfv[j_][0] = *(const bf16x8*)(bb_ + rb_ + k0);                      \
        bfv[j_][1] = *(const bf16x8*)(bb_ + rb_ + k1);                      \
      }                                                                     \
    }                                                                       \
    PRE;                                                                    \
    __builtin_amdgcn_s_barrier();                                           \
    asm volatile("s_waitcnt lgkmcnt(0)" ::: "memory");                      \
    __builtin_amdgcn_sched_barrier(0);                                      \
    __builtin_amdgcn_s_setprio(1);                                          \
    _Pragma("unroll")                                                       \
    for (int i_ = 0; i_ < 4; i_++)                                          \
      _Pragma("unroll")                                                     \
      for (int j_ = 0; j_ < 2; j_++) {                                      \
        acc[(mh) * 4 + i_][(nh) * 2 + j_] =                                 \
            __builtin_amdgcn_mfma_f32_16x16x32_bf16(                        \
                af[i_][0], bfv[j_][0], acc[(mh) * 4 + i_][(nh) * 2 + j_], 0, 0, 0); \
        acc[(mh) * 4 + i_][(nh) * 2 + j_] =                                 \
            __builtin_amdgcn_mfma_f32_16x16x32_bf16(                        \
                af[i_][1], bfv[j_][1], acc[(mh) * 4 + i_][(nh) * 2 + j_], 0, 0, 0); \
      }                                                                     \
    __builtin_amdgcn_s_setprio(0);                                          \
    POST;                                                                   \
    __builtin_amdgcn_s_barrier();                                           \
  }

template <int EPI>
__global__ __launch_bounds__(512, 2) void gemm256(const unsigned short* __restrict__ A,
                                                  const unsigned short* __restrict__ Bt,
                                                  void* __restrict__ Cout,
                                                  const float* __restrict__ uin,
                                                  const float* __restrict__ Dvec,
                                                  const float2* __restrict__ a_arr,
                                                  float2* __restrict__ carry2) {
  const int K = 1024;
  __shared__ __align__(16) unsigned short sm[65536];   // 128 KB
  char* smc = (char*)sm;

  int tid = threadIdx.x;
  int lane = tid & 63;
  int w = tid >> 6;            // 0..7
  int wr = w >> 2, wc = w & 3; // m-half / n-quarter
  int quad = lane >> 4;        // 0..3 (k-chunk)
  int mrow = lane & 15;        // row-within-frag (A) / col (C)

  int wg = blockIdx.x;
  size_t rowBase = (size_t)(wg >> 2) * 256;   // m-tile
  size_t colBase = (size_t)(wg & 3) * 256;    // n-tile

  f32x4 acc[8][4];
#pragma unroll
  for (int i = 0; i < 8; i++)
#pragma unroll
    for (int j = 0; j < 4; j++) acc[i][j] = (f32x4){0.f, 0.f, 0.f, 0.f};

  // fragment registers, live across phases (snake reuse)
  bf16x8 af[4][2], bfv[2][2];

  // staging: thread tid, load jj covers LDS chunk ci = jj*512+tid of the 32KB tile.
  // LDS (row, chunk) = (ci>>3, ci&7); source chunk pre-swizzled: cs = (tid&7)^((tid>>3)&7)
  int cs = (tid & 7) ^ ((tid >> 3) & 7);
  int rT = tid >> 3;            // 0..63 (row within 64-row group jj)
  const unsigned short* pa[4];
  const unsigned short* pb[4];
#pragma unroll
  for (int jj = 0; jj < 4; jj++) {
    pa[jj] = A  + (rowBase + jj * 64 + rT) * K + cs * 8;
    pb[jj] = Bt + (colBase + jj * 64 + rT) * K + cs * 8;
  }

  // frag-read constants: byte col = (ks*64 + quad*16) ^ ((row&7)<<4); row&7 == mrow&7
  int axor = (mrow & 7) << 4;
  int k0 = (quad * 16) ^ axor;
  int k1 = (64 + quad * 16) ^ axor;
  int aRowByte = (wr * 128 + mrow) * 128;            // + fm*2048
  int bRowByte = 32768 + (wc * 64 + mrow) * 128;     // + fn*2048

  // prologue: stage tile 0 into buffer 0, drain, sync
  STAGE_A(0, 0);
  STAGE_B(0, 0);
  asm volatile("s_waitcnt vmcnt(0)" ::: "memory");
  __builtin_amdgcn_s_barrier();

  for (int t = 0; t < 16; ++t) {
    int bufo = (t & 1) * 65536;
    int nbo = bufo ^ 65536;
    PHASE_Q(0, 0, 1, 1, if (t < 15) STAGE_A(t + 1, nbo), );
    PHASE_Q(0, 1, 0, 1, if (t < 15) STAGE_B(t + 1, nbo), );
    PHASE_Q(1, 1, 1, 0, , );
    PHASE_Q(1, 0, 0, 1, , asm volatile("s_waitcnt vmcnt(0)" ::: "memory"));
  }

  // epilogue.  C/D frag layout: m = quad*4 + r, n = mrow (within 16x16)
  if (EPI == 0) {
    // bf16 out via full 256x256 LDS transpose -> 512B-row coalesced stores
    unsigned short* O = (unsigned short*)Cout;
    __syncthreads();
#pragma unroll
    for (int fm = 0; fm < 8; fm++)
#pragma unroll
      for (int fn = 0; fn < 4; fn++)
#pragma unroll
        for (int r = 0; r < 4; r++) {
          int m_l = wr * 128 + fm * 16 + quad * 4 + r;
          int n_l = wc * 64 + fn * 16 + mrow;
          sm[m_l * 256 + n_l] = f2bf(acc[fm][fn][r]);
        }
    __syncthreads();
#pragma unroll
    for (int it = 0; it < 16; it++) {
      int cid = it * 512 + tid;          // 8192 chunks: 256 rows x 32 x 16B
      int r = cid >> 5;
      int c = cid & 31;
      uint4 v = *(const uint4*)(sm + r * 256 + c * 8);
      *(uint4*)(O + (rowBase + r) * 1024 + colBase + c * 8) = v;
    }
    // ---- fused chunk-aggregate scan (replaces k_scan1) ----
    // 512 threads = 4 chunks x 128 complex states. Reads the bf16 tile from LDS
    // (per-wave u32 reads are 2-way bank aliased = free), 64-step complex chain,
    // one float2 store per thread. Overlaps with the uint4 stores above (both
    // only READ sm; no barrier needed).
    {
      int ql = tid & 127;                 // local complex state 0..127
      int cc = tid >> 7;                  // chunk-in-tile 0..3
      int qg = (wg & 3) * 128 + ql;       // global complex state
      float2 a = a_arr[qg];
      const unsigned short* row = sm + (cc * 64) * 256 + 2 * ql;
      float tr = 0.f, ti = 0.f;
#pragma unroll 8
      for (int l = 0; l < 64; l++) {
        unsigned v = *(const unsigned*)(row + l * 256);
        float br = bf2f((unsigned short)v), bi = bf2f((unsigned short)(v >> 16));
        float nr = fmaf(a.x, tr, fmaf(-a.y, ti, br));
        ti = fmaf(a.x, ti, fmaf(a.y, tr, bi));
        tr = nr;
      }
      int b = (int)(rowBase >> 12);
      int cg = (int)((rowBase & 4095) >> 6) + cc;
      carry2[(size_t)(b * NCHUNK + cg) * 512 + qg] = make_float2(tr, ti);
    }
  } else {
    float* O = (float*)Cout;
    size_t mBase = rowBase + wr * 128 + quad * 4;
    size_t nBase = colBase + wc * 64 + mrow;
#pragma unroll
    for (int fm = 0; fm < 8; fm++)
#pragma unroll
      for (int fn = 0; fn < 4; fn++) {
        size_t n = nBase + fn * 16;
        float dv = Dvec[n];
#pragma unroll
        for (int r = 0; r < 4; r++) {
          size_t m = mBase + fm * 16 + r;
          O[m * 1024 + n] = acc[fm][fn][r] + dv * uin[m * 1024 + n];
        }
      }
  }
}

// ---------------- scan phase 2: wave-parallel Kogge-Stone over chunk carries ----------
// One wave per (b,q): lane = chunk c. Inclusive KS with uniform multiplier s^d
// (repeated squaring), then shift to exclusive. 4096 waves = 1024 blocks.
__global__ void k_scan2(const float2* __restrict__ carry2, const float2* __restrict__ aS_arr,
                        float2* __restrict__ prefix2) {
  int wid = blockIdx.x * 4 + (threadIdx.x >> 6);   // 0..4095
  int lane = threadIdx.x & 63;                     // chunk index c
  int b = wid >> 9;                                // 0..7
  int q = wid & 511;                               // 0..511
  float2 s = aS_arr[q];
  size_t o = (size_t)(b * NCHUNK + lane) * 512 + q;
  float2 T = carry2[o];
  float tr = T.x, ti = T.y;
  // inclusive scan: S_c = sum_{j<=c} s^(c-j) T_j
  float mr = s.x, mi = s.y;                        // s^d, starting d=1
#pragma unroll
  for (int d = 1; d < 64; d <<= 1) {
    float ur = __shfl_up(tr, d, 64);
    float ui = __shfl_up(ti, d, 64);
    if (lane >= d) {
      tr = fmaf(mr, ur, fmaf(-mi, ui, tr));
      ti = fmaf(mr, ui, fmaf(mi, ur, ti));
    }
    float nmr = mr * mr - mi * mi;                 // s^d -> s^(2d)
    mi = 2.f * mr * mi;
    mr = nmr;
  }
  // exclusive: prefix before chunk c = S_{c-1}; chunk 0 starts at 0
  float er = __shfl_up(tr, 1, 64);
  float ei = __shfl_up(ti, 1, 64);
  if (lane == 0) { er = 0.f; ei = 0.f; }
  prefix2[o] = make_float2(er, ei);
}

// ---------------- scan phase 3: replay chunk from carry-in, write xs bf16 ----------
// 1 chunk per 256-thread block (512 blocks), 2 complex states/thread; interleaved
// layout -> re/im arrive in ONE u32 load per (l, q).
__global__ void k_scan3(const unsigned short* __restrict__ Bu, const float2* __restrict__ a_arr,
                        const float2* __restrict__ prefix2, unsigned short* __restrict__ xs) {
  int bc = blockIdx.x;
  int t = threadIdx.x;
  int q0 = t, q1 = t + 256;
  int b = bc >> 6, c = bc & 63;
  float2 a0 = a_arr[q0], a1 = a_arr[q1];
  size_t base = ((size_t)b * Lseq + (size_t)c * CHUNK) * 1024;
  size_t po = (size_t)bc * 512;
  float2 x0 = prefix2[po + q0];
  float2 x1 = prefix2[po + q1];
  float xr0 = x0.x, xi0 = x0.y, xr1 = x1.x, xi1 = x1.y;
#pragma unroll 8
  for (int l = 0; l < CHUNK; l++) {
    unsigned v0 = *(const unsigned*)(Bu + base + (size_t)l * 1024 + 2 * q0);
    unsigned v1 = *(const unsigned*)(Bu + base + (size_t)l * 1024 + 2 * q1);
    float br0 = bf2f((unsigned short)v0), bi0 = bf2f((unsigned short)(v0 >> 16));
    float br1 = bf2f((unsigned short)v1), bi1 = bf2f((unsigned short)(v1 >> 16));
    float nr0 = fmaf(a0.x, xr0, fmaf(-a0.y, xi0, br0));
    xi0 = fmaf(a0.x, xi0, fmaf(a0.y, xr0, bi0));
    xr0 = nr0;
    float nr1 = fmaf(a1.x, xr1, fmaf(-a1.y, xi1, br1));
    xi1 = fmaf(a1.x, xi1, fmaf(a1.y, xr1, bi1));
    xr1 = nr1;
    unsigned o0 = (unsigned)f2bf(xr0) | ((unsigned)f2bf(xi0) << 16);
    unsigned o1 = (unsigned)f2bf(xr1) | ((unsigned)f2bf(xi1) << 16);
    *(unsigned*)(xs + base + (size_t)l * 1024 + 2 * q0) = o0;
    *(unsigned*)(xs + base + (size_t)l * 1024 + 2 * q1) = o1;
  }
}

extern "C" void kernel_launch(void* const* d_in, const int* in_sizes, int n_in,
                              void* d_out, int out_size, void* d_ws, size_t ws_size,
                              hipStream_t stream) {
  const float* u     = (const float*)d_in[0];
  const float* Lre   = (const float*)d_in[1];
  const float* Lim   = (const float*)d_in[2];
  const float* Bin   = (const float*)d_in[3];
  const float* Cin   = (const float*)d_in[4];
  const float* Dvec  = (const float*)d_in[5];
  const float* lstep = (const float*)d_in[6];

  char* ws = (char*)d_ws;
  // ws layout (~75.5 MB):
  unsigned short* ubf_xs = (unsigned short*)(ws);                    // 67,108,864 B (u_bf16, later reused as xs)
  unsigned short* Bbar2  = (unsigned short*)(ws + 67108864);         // 2 MB
  unsigned short* C2m    = (unsigned short*)(ws + 69206016);         // 2 MB
  float2*         carry2 = (float2*)(ws + 71303168);                 // 2 MB: [8*64][512] float2
  float2*         prefix2= (float2*)(ws + 73400320);                 // 2 MB
  float2*         a_arr  = (float2*)(ws + 75497472);
  float2*         aS_arr = (float2*)(ws + 75501568);
  float2*         g_arr  = (float2*)(ws + 75505664);

  // Bu lives in d_out (bf16, 67MB of the 134MB out buffer); dead before GEMM2 writes out.
  unsigned short* Bu = (unsigned short*)d_out;

  k_setup<<<1, 512, 0, stream>>>(Lre, Lim, lstep, a_arr, aS_arr, g_arr);
  k_prep_B<<<2048, 256, 0, stream>>>(Bin, g_arr, Bbar2);
  k_prep_C<<<2048, 256, 0, stream>>>(Cin, C2m);
  k_cvt_u<<<32768, 256, 0, stream>>>(u, ubf_xs);

  gemm256<0><<<512, 512, 0, stream>>>(ubf_xs, Bbar2, (void*)Bu, nullptr, nullptr,
                                      a_arr, carry2);

  k_scan2<<<1024, 256, 0, stream>>>(carry2, aS_arr, prefix2);
  k_scan3<<<512, 256, 0, stream>>>(Bu, a_arr, prefix2, ubf_xs);

  gemm256<1><<<512, 512, 0, stream>>>(ubf_xs, C2m, d_out, u, Dvec, nullptr, nullptr);
}